// Round 1
// baseline (1541.411 us; speedup 1.0000x reference)
//
#include <hip/hip_runtime.h>

#define N_IN   100000
#define N_OUT  200000
#define KOFF   27
#define C      64      // INC == OUTC == 64
#define EPS    1e-5f

// One wave (64 lanes) per (offset k, row r) pair.
// lane = output channel. W[k][:,lane] cached in 64 VGPRs, amortized
// over many pairs via grid-stride. feats row read as broadcast float4.
__global__ __launch_bounds__(256)
void conv_scatter_kernel(const float* __restrict__ feats,
                         const float* __restrict__ weight,
                         const int*   __restrict__ in_idx,
                         const int*   __restrict__ out_idx,
                         float*       __restrict__ out)
{
    const int k    = blockIdx.y;
    const int lane = threadIdx.x & 63;
    const int wave = threadIdx.x >> 6;                 // 0..3
    const int wavesInGrid = gridDim.x * 4;
    const int waveId      = blockIdx.x * 4 + wave;

    // Preload W[k][ci][lane] for ci = 0..63 into registers (coalesced 256B loads)
    const float* wk = weight + (size_t)k * C * C + lane;
    float w[C];
    #pragma unroll
    for (int ci = 0; ci < C; ++ci) w[ci] = wk[(size_t)ci * C];

    const int* ii_k = in_idx  + (size_t)k * N_IN;
    const int* oi_k = out_idx + (size_t)k * N_IN;

    for (int r = waveId; r < N_IN; r += wavesInGrid) {
        const int ii = ii_k[r];
        const int oi = oi_k[r];

        const float4* frow = reinterpret_cast<const float4*>(feats + (size_t)ii * C);
        float acc = 0.0f;
        #pragma unroll
        for (int j = 0; j < C / 4; ++j) {
            float4 f = frow[j];                        // broadcast load (same addr all lanes)
            acc = fmaf(f.x, w[4 * j + 0], acc);
            acc = fmaf(f.y, w[4 * j + 1], acc);
            acc = fmaf(f.z, w[4 * j + 2], acc);
            acc = fmaf(f.w, w[4 * j + 3], acc);
        }
        atomicAdd(out + (size_t)oi * C + lane, acc);   // coalesced 256B row of atomics
    }
}

// In-place eval-BatchNorm + ReLU over out [N_OUT, C], float4-vectorized.
__global__ __launch_bounds__(256)
void bn_relu_kernel(float* __restrict__ out,
                    const float* __restrict__ gamma,
                    const float* __restrict__ beta,
                    const float* __restrict__ mean,
                    const float* __restrict__ var)
{
    const int total4 = N_OUT * C / 4;
    int idx = blockIdx.x * blockDim.x + threadIdx.x;
    if (idx >= total4) return;

    const int c0 = (idx * 4) & (C - 1);
    float sc[4], sh[4];
    #pragma unroll
    for (int j = 0; j < 4; ++j) {
        const int c  = c0 + j;
        const float s = gamma[c] * rsqrtf(var[c] + EPS);
        sc[j] = s;
        sh[j] = beta[c] - mean[c] * s;
    }

    float4* p = reinterpret_cast<float4*>(out) + idx;
    float4 v = *p;
    v.x = fmaf(v.x, sc[0], sh[0]); v.x = v.x > 0.f ? v.x : 0.f;
    v.y = fmaf(v.y, sc[1], sh[1]); v.y = v.y > 0.f ? v.y : 0.f;
    v.z = fmaf(v.z, sc[2], sh[2]); v.z = v.z > 0.f ? v.z : 0.f;
    v.w = fmaf(v.w, sc[3], sh[3]); v.w = v.w > 0.f ? v.w : 0.f;
    *p = v;
}

extern "C" void kernel_launch(void* const* d_in, const int* in_sizes, int n_in,
                              void* d_out, int out_size, void* d_ws, size_t ws_size,
                              hipStream_t stream) {
    const float* feats   = (const float*)d_in[0];
    const float* weight  = (const float*)d_in[1];
    const int*   in_idx  = (const int*)  d_in[2];
    const int*   out_idx = (const int*)  d_in[3];
    const float* gamma   = (const float*)d_in[4];
    const float* beta    = (const float*)d_in[5];
    const float* rmean   = (const float*)d_in[6];
    const float* rvar    = (const float*)d_in[7];
    float* out = (float*)d_out;

    // Zero the accumulator (d_out is poisoned; we accumulate in place).
    hipMemsetAsync(out, 0, (size_t)out_size * sizeof(float), stream);

    // Conv: grid.x chosen so each wave amortizes its W-register preload
    // over ~49 pairs. 512*27 blocks * 4 waves = 55k waves.
    dim3 grid(512, KOFF);
    conv_scatter_kernel<<<grid, 256, 0, stream>>>(feats, weight, in_idx, out_idx, out);

    // Fused BN + ReLU, in place.
    const int total4 = N_OUT * C / 4;
    bn_relu_kernel<<<(total4 + 255) / 256, 256, 0, stream>>>(out, gamma, beta, rmean, rvar);
}

// Round 2
// 1534.975 us; speedup vs baseline: 1.0042x; 1.0042x over previous
//
#include <hip/hip_runtime.h>
#include <hip/hip_bf16.h>
#include <stdint.h>

#define NIN    100000
#define NOUT   200000
#define KOFF   27
#define C      64
#define NPAIR  (KOFF * NIN)      // 2,700,000
#define EPS    1e-5f
#define NB_SCAN ((NOUT + 255) / 256)   // 782

// ---------------- Phase A: dense GEMM  P[k] = feats @ W[k]  (bf16 out) -----
// One wave per (k, row). lane = out channel; W[k][:,lane] in 64 VGPRs.
__global__ __launch_bounds__(256)
void gemm_p_kernel(const float* __restrict__ feats,
                   const float* __restrict__ weight,
                   __hip_bfloat16* __restrict__ P)
{
    const int k    = blockIdx.y;
    const int lane = threadIdx.x & 63;
    const int wave = threadIdx.x >> 6;
    const int wavesInGrid = gridDim.x * 4;
    const int waveId      = blockIdx.x * 4 + wave;

    const float* wk = weight + (size_t)k * C * C + lane;
    float w[C];
    #pragma unroll
    for (int ci = 0; ci < C; ++ci) w[ci] = wk[(size_t)ci * C];

    __hip_bfloat16* Pk = P + (size_t)k * NIN * C;

    for (int r = waveId; r < NIN; r += wavesInGrid) {
        const float4* frow = reinterpret_cast<const float4*>(feats + (size_t)r * C);
        float acc = 0.0f;
        #pragma unroll
        for (int j = 0; j < C / 4; ++j) {
            float4 f = frow[j];                       // broadcast load
            acc = fmaf(f.x, w[4 * j + 0], acc);
            acc = fmaf(f.y, w[4 * j + 1], acc);
            acc = fmaf(f.z, w[4 * j + 2], acc);
            acc = fmaf(f.w, w[4 * j + 3], acc);
        }
        Pk[(size_t)r * C + lane] = __float2bfloat16(acc);
    }
}

// ---------------- Phase B: CSR reverse map ---------------------------------
__global__ __launch_bounds__(256)
void count_kernel(const int* __restrict__ out_idx, int* __restrict__ counts)
{
    int t = blockIdx.x * 256 + threadIdx.x;
    if (t < NPAIR) atomicAdd(&counts[out_idx[t]], 1);
}

__global__ __launch_bounds__(256)
void scan1_kernel(const int* __restrict__ counts, int* __restrict__ offsets,
                  int* __restrict__ blocksums)
{
    __shared__ int s[256];
    const int t = threadIdx.x;
    const int gid = blockIdx.x * 256 + t;
    int v = (gid < NOUT) ? counts[gid] : 0;
    s[t] = v;
    __syncthreads();
    for (int off = 1; off < 256; off <<= 1) {
        int x = (t >= off) ? s[t - off] : 0;
        __syncthreads();
        s[t] += x;
        __syncthreads();
    }
    if (gid < NOUT) offsets[gid] = s[t] - v;          // block-local exclusive
    if (t == 255) blocksums[blockIdx.x] = s[255];     // block total
}

__global__ __launch_bounds__(1024)
void scan2_kernel(int* __restrict__ blocksums, int* __restrict__ offsets)
{
    __shared__ int s[1024];
    const int t = threadIdx.x;
    int v = (t < NB_SCAN) ? blocksums[t] : 0;
    s[t] = v;
    __syncthreads();
    for (int off = 1; off < 1024; off <<= 1) {
        int x = (t >= off) ? s[t - off] : 0;
        __syncthreads();
        s[t] += x;
        __syncthreads();
    }
    if (t < NB_SCAN) blocksums[t] = s[t] - v;         // exclusive
    if (t == NB_SCAN - 1) offsets[NOUT] = s[t];       // grand total
}

__global__ __launch_bounds__(256)
void scan3_kernel(int* __restrict__ offsets, const int* __restrict__ blocksums,
                  int* __restrict__ cursor)
{
    int gid = blockIdx.x * 256 + threadIdx.x;
    if (gid < NOUT) {
        int o = offsets[gid] + blocksums[blockIdx.x];
        offsets[gid] = o;
        cursor[gid]  = o;
    }
}

__global__ __launch_bounds__(256)
void fill_kernel(const int* __restrict__ in_idx, const int* __restrict__ out_idx,
                 int* __restrict__ cursor, int* __restrict__ pairlist)
{
    int t = blockIdx.x * 256 + threadIdx.x;
    if (t < NPAIR) {
        int oi  = out_idx[t];
        int pos = atomicAdd(&cursor[oi], 1);
        int k   = t / NIN;
        pairlist[pos] = k * NIN + in_idx[t];          // P row to gather
    }
}

// ---------------- Phase C: gather-reduce + BN + ReLU -----------------------
// 32 threads per output row; each owns a bf16x2 channel pair (4B loads).
__global__ __launch_bounds__(256)
void gather_bn_relu_kernel(const uint32_t* __restrict__ P32,
                           const int* __restrict__ offsets,
                           const int* __restrict__ pairlist,
                           const float* __restrict__ gamma,
                           const float* __restrict__ beta,
                           const float* __restrict__ mean,
                           const float* __restrict__ var,
                           float* __restrict__ out)
{
    int tid = blockIdx.x * 256 + threadIdx.x;
    int row = tid >> 5;
    int cp  = tid & 31;
    if (row >= NOUT) return;

    const int beg = offsets[row];
    const int end = offsets[row + 1];

    float a0 = 0.f, a1 = 0.f;
    int j = beg;
    for (; j + 1 < end; j += 2) {                     // 2 loads in flight
        int p0 = pairlist[j];
        int p1 = pairlist[j + 1];
        uint32_t u0 = P32[(size_t)p0 * 32 + cp];
        uint32_t u1 = P32[(size_t)p1 * 32 + cp];
        a0 += __uint_as_float(u0 << 16);
        a1 += __uint_as_float(u0 & 0xffff0000u);
        a0 += __uint_as_float(u1 << 16);
        a1 += __uint_as_float(u1 & 0xffff0000u);
    }
    if (j < end) {
        uint32_t u0 = P32[(size_t)pairlist[j] * 32 + cp];
        a0 += __uint_as_float(u0 << 16);
        a1 += __uint_as_float(u0 & 0xffff0000u);
    }

    const int c0 = cp * 2;
    float s0 = gamma[c0]     * rsqrtf(var[c0]     + EPS);
    float s1 = gamma[c0 + 1] * rsqrtf(var[c0 + 1] + EPS);
    float y0 = fmaf(a0, s0, beta[c0]     - mean[c0]     * s0);
    float y1 = fmaf(a1, s1, beta[c0 + 1] - mean[c0 + 1] * s1);
    y0 = y0 > 0.f ? y0 : 0.f;
    y1 = y1 > 0.f ? y1 : 0.f;
    reinterpret_cast<float2*>(out)[(size_t)row * 32 + cp] = make_float2(y0, y1);
}

// ---------------- Fallback (round-1 path) ----------------------------------
__global__ __launch_bounds__(256)
void conv_scatter_kernel(const float* __restrict__ feats,
                         const float* __restrict__ weight,
                         const int*   __restrict__ in_idx,
                         const int*   __restrict__ out_idx,
                         float*       __restrict__ out)
{
    const int k    = blockIdx.y;
    const int lane = threadIdx.x & 63;
    const int wave = threadIdx.x >> 6;
    const int wavesInGrid = gridDim.x * 4;
    const int waveId      = blockIdx.x * 4 + wave;

    const float* wk = weight + (size_t)k * C * C + lane;
    float w[C];
    #pragma unroll
    for (int ci = 0; ci < C; ++ci) w[ci] = wk[(size_t)ci * C];

    const int* ii_k = in_idx  + (size_t)k * NIN;
    const int* oi_k = out_idx + (size_t)k * NIN;

    for (int r = waveId; r < NIN; r += wavesInGrid) {
        const int ii = ii_k[r];
        const int oi = oi_k[r];
        const float4* frow = reinterpret_cast<const float4*>(feats + (size_t)ii * C);
        float acc = 0.0f;
        #pragma unroll
        for (int j = 0; j < C / 4; ++j) {
            float4 f = frow[j];
            acc = fmaf(f.x, w[4 * j + 0], acc);
            acc = fmaf(f.y, w[4 * j + 1], acc);
            acc = fmaf(f.z, w[4 * j + 2], acc);
            acc = fmaf(f.w, w[4 * j + 3], acc);
        }
        atomicAdd(out + (size_t)oi * C + lane, acc);
    }
}

__global__ __launch_bounds__(256)
void bn_relu_kernel(float* __restrict__ out,
                    const float* __restrict__ gamma,
                    const float* __restrict__ beta,
                    const float* __restrict__ mean,
                    const float* __restrict__ var)
{
    const int total4 = NOUT * C / 4;
    int idx = blockIdx.x * blockDim.x + threadIdx.x;
    if (idx >= total4) return;
    const int c0 = (idx * 4) & (C - 1);
    float sc[4], sh[4];
    #pragma unroll
    for (int j = 0; j < 4; ++j) {
        const int c  = c0 + j;
        const float s = gamma[c] * rsqrtf(var[c] + EPS);
        sc[j] = s;
        sh[j] = beta[c] - mean[c] * s;
    }
    float4* p = reinterpret_cast<float4*>(out) + idx;
    float4 v = *p;
    v.x = fmaf(v.x, sc[0], sh[0]); v.x = v.x > 0.f ? v.x : 0.f;
    v.y = fmaf(v.y, sc[1], sh[1]); v.y = v.y > 0.f ? v.y : 0.f;
    v.z = fmaf(v.z, sc[2], sh[2]); v.z = v.z > 0.f ? v.z : 0.f;
    v.w = fmaf(v.w, sc[3], sh[3]); v.w = v.w > 0.f ? v.w : 0.f;
    *p = v;
}

// ---------------------------------------------------------------------------
extern "C" void kernel_launch(void* const* d_in, const int* in_sizes, int n_in,
                              void* d_out, int out_size, void* d_ws, size_t ws_size,
                              hipStream_t stream) {
    const float* feats   = (const float*)d_in[0];
    const float* weight  = (const float*)d_in[1];
    const int*   in_idx  = (const int*)  d_in[2];
    const int*   out_idx = (const int*)  d_in[3];
    const float* gamma   = (const float*)d_in[4];
    const float* beta    = (const float*)d_in[5];
    const float* rmean   = (const float*)d_in[6];
    const float* rvar    = (const float*)d_in[7];
    float* out = (float*)d_out;

    // ws layout (256B-aligned slices)
    const size_t szP     = (size_t)NPAIR * C * sizeof(__hip_bfloat16);   // 345.6 MB
    const size_t szCnt   = (size_t)NOUT * sizeof(int);
    const size_t szOff   = (size_t)(NOUT + 1) * sizeof(int);
    const size_t szCur   = (size_t)NOUT * sizeof(int);
    const size_t szBlk   = 1024 * sizeof(int);
    const size_t szPair  = (size_t)NPAIR * sizeof(int);
    auto align = [](size_t x) { return (x + 255) & ~(size_t)255; };
    size_t o0 = 0;
    size_t oP    = o0;              o0 += align(szP);
    size_t oCnt  = o0;              o0 += align(szCnt);
    size_t oOff  = o0;              o0 += align(szOff);
    size_t oCur  = o0;              o0 += align(szCur);
    size_t oBlk  = o0;              o0 += align(szBlk);
    size_t oPair = o0;              o0 += align(szPair);

    if (ws_size < o0) {
        // Fallback: atomic-scatter path (round-1)
        hipMemsetAsync(out, 0, (size_t)out_size * sizeof(float), stream);
        dim3 grid(512, KOFF);
        conv_scatter_kernel<<<grid, 256, 0, stream>>>(feats, weight, in_idx, out_idx, out);
        const int total4 = NOUT * C / 4;
        bn_relu_kernel<<<(total4 + 255) / 256, 256, 0, stream>>>(out, gamma, beta, rmean, rvar);
        return;
    }

    char* ws = (char*)d_ws;
    __hip_bfloat16* P   = (__hip_bfloat16*)(ws + oP);
    int* counts   = (int*)(ws + oCnt);
    int* offsets  = (int*)(ws + oOff);
    int* cursor   = (int*)(ws + oCur);
    int* blksums  = (int*)(ws + oBlk);
    int* pairlist = (int*)(ws + oPair);

    // Phase A: dense GEMM into P (no atomics)
    {
        dim3 grid(512, KOFF);
        gemm_p_kernel<<<grid, 256, 0, stream>>>(feats, weight, P);
    }

    // Phase B: CSR reverse map
    hipMemsetAsync(counts, 0, szCnt, stream);
    {
        int nb = (NPAIR + 255) / 256;
        count_kernel<<<nb, 256, 0, stream>>>(out_idx, counts);
        scan1_kernel<<<NB_SCAN, 256, 0, stream>>>(counts, offsets, blksums);
        scan2_kernel<<<1, 1024, 0, stream>>>(blksums, offsets);
        scan3_kernel<<<NB_SCAN, 256, 0, stream>>>(offsets, blksums, cursor);
        fill_kernel<<<nb, 256, 0, stream>>>(in_idx, out_idx, cursor, pairlist);
    }

    // Phase C: gather-reduce + BN + ReLU (writes d_out exactly once)
    {
        int nthreads = NOUT * 32;
        gather_bn_relu_kernel<<<(nthreads + 255) / 256, 256, 0, stream>>>(
            (const uint32_t*)P, offsets, pairlist, gamma, beta, rmean, rvar, out);
    }
}